// Round 2
// baseline (297.727 us; speedup 1.0000x reference)
//
#include <hip/hip_runtime.h>
#include <hip/hip_bf16.h>
#include <math.h>

#define T_LEN 2048
#define TE_LEN 1024
#define D_DIM 1024
#define H_NUM 16
#define HD_DIM 64
#define R_PAD 64  // zero rows appended to R for u>T-1 (masked) selections

typedef unsigned short ushort;
typedef __attribute__((ext_vector_type(8))) short short8;    // 8 x bf16 MFMA frag
typedef __attribute__((ext_vector_type(4))) float f32x4;     // MFMA acc frag
typedef __attribute__((ext_vector_type(4))) ushort ushort4v;

__device__ __forceinline__ ushort f2b(float f) {  // fp32 -> bf16 RNE
    unsigned u = __builtin_bit_cast(unsigned, f);
    u += 0x7fffu + ((u >> 16) & 1u);
    return (ushort)(u >> 16);
}
__device__ __forceinline__ float b2f(ushort s) {
    unsigned u = ((unsigned)s) << 16;
    return __builtin_bit_cast(float, u);
}

// async global->LDS copy, 16B per lane: lands at (wave-uniform) ldsbase + lane*16.
__device__ __forceinline__ void gld16(const ushort* g, ushort* l) {
    __builtin_amdgcn_global_load_lds(
        (const __attribute__((address_space(1))) unsigned int*)g,
        (__attribute__((address_space(3))) unsigned int*)l, 16, 0, 0);
}

union U8 { short8 v; ushort u[8]; };

// ---------------------------------------------------------------------------
// prep: pos emb (bf16) + x/extra fp32->bf16 casts, one dispatch.
// ---------------------------------------------------------------------------
__global__ void prep_kernel(const float* __restrict__ x, const float* __restrict__ extra,
                            ushort* __restrict__ pos, ushort* __restrict__ xb,
                            ushort* __restrict__ eb) {
    const int q = blockIdx.x * 256 + threadIdx.x;  // quad index
    const int PQ = 524288;        // pos quads (2M elems)
    const int XQ = 1048576;       // + x quads (2M elems)
    if (q < PQ) {
        int idx = q * 4;
        int i = idx >> 10, j = idx & 1023;
        bool sinreg = (j < 512);
        int jj = sinreg ? j : j - 512;
        float p = (float)(2047 - i);
        ushort4v o;
#pragma unroll
        for (int u = 0; u < 4; u++) {
            // -(2/1024)*log2(10000) = -0.025952563241
            float inv = exp2f((float)(jj + u) * -0.025952563241f);
            float fa = p * inv;
            ((ushort*)&o)[u] = f2b(sinreg ? sinf(fa) : cosf(fa));
        }
        *(ushort4v*)&pos[idx] = o;
    } else if (q < XQ) {
        int idx = (q - PQ) * 4;
        float4 v = *(const float4*)&x[idx];
        ushort4v o = {f2b(v.x), f2b(v.y), f2b(v.z), f2b(v.w)};
        *(ushort4v*)&xb[idx] = o;
    } else {
        int idx = (q - XQ) * 4;
        float4 v = *(const float4*)&extra[idx];
        ushort4v o = {f2b(v.x), f2b(v.y), f2b(v.z), f2b(v.w)};
        *(ushort4v*)&eb[idx] = o;
    }
}

// 7 weight transposes + R-pad zeroing in ONE dispatch (z=0..6 transpose, z=7 zero).
__global__ __launch_bounds__(256) void transpose7_kernel(
    const float* __restrict__ W0, const float* __restrict__ W1,
    const float* __restrict__ W2, const float* __restrict__ W3,
    const float* __restrict__ W4, const float* __restrict__ W5,
    const float* __restrict__ W6, ushort* __restrict__ out,
    ushort* __restrict__ Rpad) {
    if (blockIdx.z == 7) {
        int gid = (blockIdx.y * 32 + blockIdx.x) * 256 + threadIdx.x;
        if (gid < (R_PAD * 1024) / 8) {
            short8 z = {0, 0, 0, 0, 0, 0, 0, 0};
            *(short8*)&Rpad[gid * 8] = z;
        }
        return;
    }
    const float* Ws[7] = {W0, W1, W2, W3, W4, W5, W6};
    const float* W = Ws[blockIdx.z];
    ushort* WT = out + (size_t)blockIdx.z * (1024 * 1024);
    __shared__ float tile[32][33];
    int c0 = blockIdx.x * 32, r0 = blockIdx.y * 32;
    int tid = threadIdx.x;
#pragma unroll
    for (int p = 0; p < 4; p++) {
        int idx = tid + p * 256;
        int r = idx >> 5, c = idx & 31;
        tile[r][c] = W[(size_t)(r0 + r) * D_DIM + c0 + c];
    }
    __syncthreads();
#pragma unroll
    for (int p = 0; p < 4; p++) {
        int idx = tid + p * 256;
        int r = idx >> 5, c = idx & 31;
        WT[(size_t)(c0 + r) * D_DIM + r0 + c] = f2b(tile[c][r]);
    }
}

// ---------------------------------------------------------------------------
// Mega-GEMM (m97 structure): QKV (384) + R (128) + EK|EV (128) = 640 blocks.
// 128x128 tile, BK=64, K=1024. Single-buffer LDS (32KB -> 4 blocks/CU),
// 2 barriers/ktile, gld16 async staging with XOR chunk-swizzle (2-way free).
// ---------------------------------------------------------------------------
__global__ __launch_bounds__(256) void gemm_mega(
    const ushort* __restrict__ xb, const ushort* __restrict__ posb,
    const ushort* __restrict__ eb, const ushort* __restrict__ WT,
    ushort* __restrict__ Qb, ushort* __restrict__ Kb, ushort* __restrict__ VTb,
    ushort* __restrict__ Rb, ushort* __restrict__ EKb, ushort* __restrict__ EVTb) {
    __shared__ ushort As[128 * 64];   // [row][chunk^(row&7)] 16KB
    __shared__ ushort Bs[128 * 64];
    const int tid = threadIdx.x;
    const int lane = tid & 63, w = tid >> 6;
    const int l15 = lane & 15, quad = lane >> 4;
    const int wm = w & 1, wn = w >> 1;
    const size_t M1 = 1024 * 1024;

    int idx = blockIdx.x;
    const ushort *A, *BT;
    ushort* dst;
    int m0, nb0, nc0, ldt = 1024;
    bool transp = false;
    if (idx < 384) {                       // QKV: x @ [Wq|Wk|Wv]
        m0 = (idx & 15) * 128; nb0 = (idx >> 4) * 128;
        A = xb; BT = WT;
        nc0 = nb0 & 1023;
        int seg = nb0 >> 10;
        if (seg == 0) dst = Qb;
        else if (seg == 1) dst = Kb;
        else { dst = VTb; transp = true; ldt = T_LEN; }
    } else if (idx < 512) {                // R: pos @ Wr
        int i = idx - 384;
        m0 = (i & 15) * 128; nb0 = (i >> 4) * 128; nc0 = nb0;
        A = posb; BT = WT + 5 * M1; dst = Rb;
    } else {                               // EK|EV: extra @ [Wek|Wev]
        int i = idx - 512;
        m0 = (i & 7) * 128; nb0 = (i >> 3) * 128; nc0 = nb0 & 1023;
        A = eb; BT = WT + 3 * M1;
        if (nb0 < 1024) dst = EKb;
        else { dst = EVTb; transp = true; ldt = TE_LEN; }
    }

    f32x4 acc[16];
#pragma unroll
    for (int i = 0; i < 16; i++) acc[i] = (f32x4){0.f, 0.f, 0.f, 0.f};

    for (int k0 = 0; k0 < 1024; k0 += 64) {
        __syncthreads();   // previous ktile's ds_reads done
#pragma unroll
        for (int i = 0; i < 4; i++) {
            int ci = i * 256 + tid;
            int row = ci >> 3, cs = (ci & 7) ^ (row & 7);
            gld16(A + (size_t)(m0 + row) * 1024 + k0 + cs * 8, &As[(i * 32 + w * 8) * 64]);
            gld16(BT + (size_t)(nb0 + row) * 1024 + k0 + cs * 8, &Bs[(i * 32 + w * 8) * 64]);
        }
        __syncthreads();   // staging landed (vmcnt drained by barrier)
#pragma unroll
        for (int kc = 0; kc < 2; kc++) {
            short8 bfr[4];
#pragma unroll
            for (int nf = 0; nf < 4; nf++) {
                const int row = wn * 64 + nf * 16 + l15;
                bfr[nf] = *(const short8*)&Bs[(row * 8 + ((kc * 4 + quad) ^ (row & 7))) * 8];
            }
#pragma unroll
            for (int mf = 0; mf < 4; mf++) {
                const int row = wm * 64 + mf * 16 + l15;
                short8 afr = *(const short8*)&As[(row * 8 + ((kc * 4 + quad) ^ (row & 7))) * 8];
#pragma unroll
                for (int nf = 0; nf < 4; nf++)
                    acc[mf * 4 + nf] = __builtin_amdgcn_mfma_f32_16x16x32_bf16(afr, bfr[nf], acc[mf * 4 + nf], 0, 0, 0);
            }
        }
    }

#pragma unroll
    for (int mf = 0; mf < 4; mf++) {
#pragma unroll
        for (int nf = 0; nf < 4; nf++) {
            f32x4 a = acc[mf * 4 + nf];
            const int mrow = m0 + wm * 64 + mf * 16 + quad * 4;
            const int nc = nc0 + wn * 64 + nf * 16 + l15;
            if (transp) {
                ushort4v v = {f2b(a[0]), f2b(a[1]), f2b(a[2]), f2b(a[3])};
                *(ushort4v*)&dst[(size_t)nc * ldt + mrow] = v;
            } else {
#pragma unroll
                for (int r = 0; r < 4; r++) dst[(size_t)(mrow + r) * 1024 + nc] = f2b(a[r]);
            }
        }
    }
}

// ---------------------------------------------------------------------------
// Wo GEMM (m97 structure): out[2048][1024] fp32 = AO @ Wo. 128x64 -> 256 blocks.
// ---------------------------------------------------------------------------
__global__ __launch_bounds__(256) void gemm_wo(const ushort* __restrict__ A,
                                               const ushort* __restrict__ BT,
                                               float* __restrict__ out) {
    __shared__ ushort As[128 * 64];
    __shared__ ushort Bs[64 * 64];
    const int tid = threadIdx.x;
    const int lane = tid & 63, w = tid >> 6;
    const int l15 = lane & 15, quad = lane >> 4;
    const int wm = w & 1, wn = w >> 1;  // 2x2 waves: 64 rows x 32 cols each
    const int m0 = blockIdx.y * 128, n0 = blockIdx.x * 64;

    f32x4 acc[8];
#pragma unroll
    for (int i = 0; i < 8; i++) acc[i] = (f32x4){0.f, 0.f, 0.f, 0.f};

    for (int k0 = 0; k0 < 1024; k0 += 64) {
        __syncthreads();
#pragma unroll
        for (int i = 0; i < 4; i++) {
            int ci = i * 256 + tid;
            int row = ci >> 3, cs = (ci & 7) ^ (row & 7);
            gld16(A + (size_t)(m0 + row) * 1024 + k0 + cs * 8, &As[(i * 32 + w * 8) * 64]);
        }
#pragma unroll
        for (int i = 0; i < 2; i++) {
            int ci = i * 256 + tid;
            int row = ci >> 3, cs = (ci & 7) ^ (row & 7);
            gld16(BT + (size_t)(n0 + row) * 1024 + k0 + cs * 8, &Bs[(i * 32 + w * 8) * 64]);
        }
        __syncthreads();
#pragma unroll
        for (int kc = 0; kc < 2; kc++) {
            short8 bfr[2];
#pragma unroll
            for (int nf = 0; nf < 2; nf++) {
                const int row = wn * 32 + nf * 16 + l15;
                bfr[nf] = *(const short8*)&Bs[(row * 8 + ((kc * 4 + quad) ^ (row & 7))) * 8];
            }
#pragma unroll
            for (int mf = 0; mf < 4; mf++) {
                const int row = wm * 64 + mf * 16 + l15;
                short8 afr = *(const short8*)&As[(row * 8 + ((kc * 4 + quad) ^ (row & 7))) * 8];
#pragma unroll
                for (int nf = 0; nf < 2; nf++)
                    acc[mf * 2 + nf] = __builtin_amdgcn_mfma_f32_16x16x32_bf16(afr, bfr[nf], acc[mf * 2 + nf], 0, 0, 0);
            }
        }
    }

#pragma unroll
    for (int mf = 0; mf < 4; mf++) {
#pragma unroll
        for (int nf = 0; nf < 2; nf++) {
            f32x4 a = acc[mf * 2 + nf];
            const int mrow = m0 + wm * 64 + mf * 16 + quad * 4;
            const int nc = n0 + wn * 32 + nf * 16 + l15;
#pragma unroll
            for (int r = 0; r < 4; r++) out[(size_t)(mrow + r) * 1024 + nc] = a[r];
        }
    }
}

// ---------------------------------------------------------------------------
// Fused flash attention, 2-way KEY-SPLIT, 512 threads = two 4-wave groups.
// R1 change: R fragments are read DIRECTLY from global (L2-resident slice,
// ~270KB/head, 2 heads/XCD) instead of LDS-staged -- deletes the 32KB
// circular buffer + stageR, and rel cf=0 is carried in a register from the
// previous tile's cf=2 (identical R rows x same qr). LDS 74KB -> 42KB so
// 2-3 blocks/CU co-schedule (was 1), and LDS-pipe work per tile drops ~25%.
// Fixed-max softmax partials combine by addition: group 1 passes (O, sum p)
// through LDS (aliasing dead K/V bufs) and group 0 normalizes + stores.
// ---------------------------------------------------------------------------
__global__ __launch_bounds__(512, 4) void attn_kernel(
    const ushort* __restrict__ Qb, const ushort* __restrict__ Kb,
    const ushort* __restrict__ VT, const ushort* __restrict__ Rb,
    const ushort* __restrict__ EKb, const ushort* __restrict__ EVT,
    const float* __restrict__ rwb, const float* __restrict__ rrb,
    ushort* __restrict__ AOb) {
    // LDS carve (ushort units):
    //   [    0, 8192) Kst: g*4096 + buf*2048   (2 groups x 2 bufs x 32x64)
    //   [ 8192,16384) Vst: g*4096 + buf*2048   (2 groups x 2 bufs x 64x32)
    //   [16384,21504) Plds: w*640              (8 waves x 16x40)
    //   exchange (post-loop, aliases dead K/V): exch f32[64][65] @0 (8320 us),
    //   exl f32[64] @12288.
    __shared__ __align__(16) ushort lds[21504];

    const int tid = threadIdx.x;
    const int lane = tid & 63, w = tid >> 6;
    const int g = w >> 2, wl = w & 3;      // group, group-local wave
    const int gtid = tid & 255;            // group-local thread id
    const int l15 = lane & 15, quad = lane >> 4;
    const int blk = blockIdx.x;
    const int xcd = blk & 7, rnd = blk >> 8, slot = (blk >> 3) & 31;
    const int h = xcd * 2 + rnd;
    const int qt = rnd ? slot : 31 - slot;
    const int t0 = qt * 64, tf = t0 + wl * 16;
    const int hbase = h * HD_DIM;
    const int base0 = 1984 - t0;           // R row of (group 0) band origin
    const int ninl = qt + 1;               // in-seq tiles per group
    const int ntotl = ninl + 16;           // + 16 extra tiles per group
    const int tt_s = g * ninl;             // group's first global in-seq tile
    const int baseg = base0 + 32 * tt_s;   // R row origin for this group

    ushort* Kst = lds + g * 4096;          // [buf*2048 + ...]
    ushort* Vst = lds + 8192 + g * 4096;
    ushort* Pw  = lds + 16384 + w * 640;   // this wave's 16x40 P tile

    // A-frags pre-scaled by 1/sqrt(HD)=0.125 (both groups load same Q rows):
    short8 qw[2], qr[2], qp[2];
#pragma unroll
    for (int kh = 0; kh < 2; kh++) {
        int dof = hbase + kh * 32 + quad * 8;
        U8 raw; raw.v = *(const short8*)&Qb[(size_t)(tf + l15) * D_DIM + dof];
        U8 a, b, c;
#pragma unroll
        for (int j = 0; j < 8; j++) {
            float f = b2f(raw.u[j]);
            a.u[j] = f2b((f + rwb[dof + j]) * 0.125f);
            b.u[j] = f2b((f + rrb[dof + j]) * 0.125f);
            c.u[j] = f2b(f * 0.125f);
        }
        qw[kh] = a.v; qr[kh] = b.v; qp[kh] = c.v;
    }

    float lr[4] = {0.f, 0.f, 0.f, 0.f};
    f32x4 O[4];
#pragma unroll
    for (int i = 0; i < 4; i++) O[i] = (f32x4){0.f, 0.f, 0.f, 0.f};
    f32x4 rel_carry = (f32x4){0.f, 0.f, 0.f, 0.f};

    auto stageKV = [&](int i2, int buf) {   // i2 = group-local tile index
        const bool ins = i2 < ninl;
        const int j0 = ins ? (tt_s + i2) * 32 : (g * 16 + (i2 - ninl)) * 32;
        const ushort* ksrc = ins ? Kb : EKb;
        const ushort* vsrc = ins ? VT : EVT;
        const int ldv = ins ? T_LEN : TE_LEN;
        {   // K: 32 rows x 8 chunks, 1 op/thread (group = 256 threads)
            int row = gtid >> 3, cs = (gtid & 7) ^ (row & 7);
            gld16(ksrc + (size_t)(j0 + row) * 1024 + hbase + cs * 8,
                  &Kst[buf * 2048 + wl * 512]);
        }
        {   // V: 64 rows x 4 chunks, 1 op/thread
            int row = gtid >> 2, cs = (gtid & 3) ^ (row & 3);
            gld16(vsrc + (size_t)(hbase + row) * ldv + j0 + cs * 8,
                  &Vst[buf * 2048 + wl * 512]);
        }
    };

    stageKV(0, 0);

    // per-r constants for the band shift (loop-invariant)
    int srcA[4]; bool lowcA[4];
#pragma unroll
    for (int r = 0; r < 4; r++) {
        const int m = quad * 4 + r;
        const int cb = 15 - m + l15;  // band col in [0,30]
        srcA[r] = (lane & 48) | (cb & 15);
        lowcA[r] = (cb < 16);
    }

#pragma unroll 1
    for (int i = 0; i < ntotl; i++) {
        const int b = i & 1;
        __syncthreads();                  // stage(i) landed; buf 1-b free
        if (i + 1 < ntotl) stageKV(i + 1, 1 - b);

        const bool ins = i < ninl;
        const int j0 = (tt_s + i) * 32;   // only meaningful when ins

        // R band fragments DIRECT from global (L2-resident). Issued here so
        // the ~200cy L2 latency hides under the QK^T MFMAs below. cf=0 is
        // carried from the previous tile's cf=2 (same R rows, same qr).
        short8 rf1[2], rf2[2], rf0[2];
        if (ins) {
            const size_t rbase =
                (size_t)(baseg + 48 - 16 * wl + 32 * i + l15) * 1024 + hbase + quad * 8;
#pragma unroll
            for (int kh = 0; kh < 2; kh++) {
                rf1[kh] = *(const short8*)&Rb[rbase + 16 * 1024 + kh * 32];
                rf2[kh] = *(const short8*)&Rb[rbase + 32 * 1024 + kh * 32];
            }
            if (i == 0) {
#pragma unroll
                for (int kh = 0; kh < 2; kh++)
                    rf0[kh] = *(const short8*)&Rb[rbase + kh * 32];
            }
        }

        f32x4 con[2];
#pragma unroll
        for (int c = 0; c < 2; c++) con[c] = (f32x4){0.f, 0.f, 0.f, 0.f};
#pragma unroll
        for (int kh = 0; kh < 2; kh++) {
            const short8* qa = ins ? &qw[kh] : &qp[kh];
#pragma unroll
            for (int nh = 0; nh < 2; nh++) {
                const int row = nh * 16 + l15;
                short8 kf = *(const short8*)&Kst[b * 2048 + (row * 8 + ((kh * 4 + quad) ^ (row & 7))) * 8];
                con[nh] = __builtin_amdgcn_mfma_f32_16x16x32_bf16(*qa, kf, con[nh], 0, 0, 0);
            }
        }

        if (ins) {
            f32x4 relA, rel1, rel2;
            rel1 = (f32x4){0.f, 0.f, 0.f, 0.f};
            rel2 = (f32x4){0.f, 0.f, 0.f, 0.f};
            if (i == 0) {
                relA = (f32x4){0.f, 0.f, 0.f, 0.f};
#pragma unroll
                for (int kh = 0; kh < 2; kh++)
                    relA = __builtin_amdgcn_mfma_f32_16x16x32_bf16(qr[kh], rf0[kh], relA, 0, 0, 0);
            } else {
                relA = rel_carry;
            }
#pragma unroll
            for (int kh = 0; kh < 2; kh++) {
                rel1 = __builtin_amdgcn_mfma_f32_16x16x32_bf16(qr[kh], rf1[kh], rel1, 0, 0, 0);
                rel2 = __builtin_amdgcn_mfma_f32_16x16x32_bf16(qr[kh], rf2[kh], rel2, 0, 0, 0);
            }
            rel_carry = rel2;

            const bool needmask = (j0 + 31 > tf);
#pragma unroll
            for (int r = 0; r < 4; r++) {
                const int m = quad * 4 + r;
                float b0 = __shfl(relA[r], srcA[r]);
                float b1 = __shfl(rel1[r], srcA[r]);
                float b2 = __shfl(rel2[r], srcA[r]);
                float rv0 = lowcA[r] ? b0 : b1, rv1 = lowcA[r] ? b1 : b2;
                float p0 = __expf(con[0][r] + rv0);
                float p1 = __expf(con[1][r] + rv1);
                if (needmask) {
                    const int t = tf + m;
                    if (j0 + l15 > t)      p0 = 0.f;
                    if (j0 + 16 + l15 > t) p1 = 0.f;
                }
                lr[r] += p0 + p1;
                Pw[m * 40 + l15]      = f2b(p0);
                Pw[m * 40 + 16 + l15] = f2b(p1);
            }
        } else {
#pragma unroll
            for (int r = 0; r < 4; r++) {
                const int m = quad * 4 + r;
                float p0 = __expf(con[0][r]);
                float p1 = __expf(con[1][r]);
                lr[r] += p0 + p1;
                Pw[m * 40 + l15]      = f2b(p0);
                Pw[m * 40 + 16 + l15] = f2b(p1);
            }
        }

        short8 pa = *(const short8*)&Pw[l15 * 40 + quad * 8];
#pragma unroll
        for (int df = 0; df < 4; df++) {
            const int row = df * 16 + l15;
            short8 vb = *(const short8*)&Vst[b * 2048 + (row * 4 + (quad ^ (row & 3))) * 8];
            O[df] = __builtin_amdgcn_mfma_f32_16x16x32_bf16(pa, vb, O[df], 0, 0, 0);
        }
    }

    // ---- finalize: reduce lr over the 16 j-lanes, cross-group combine ----
#pragma unroll
    for (int r = 0; r < 4; r++)
#pragma unroll
        for (int dd = 1; dd < 16; dd <<= 1) lr[r] += __shfl_xor(lr[r], dd);

    float* exch = (float*)(lds);          // 64x65 f32 (pad-65 kills bank conflicts)
    float* exl  = (float*)(lds + 12288);  // 64 f32 row sums
    __syncthreads();                      // all tiles done; safe to alias LDS
    if (g == 1) {
#pragma unroll
        for (int r = 0; r < 4; r++) {
            const int row = wl * 16 + quad * 4 + r;
            if (l15 == 0) exl[row] = lr[r];
#pragma unroll
            for (int df = 0; df < 4; df++)
                exch[row * 65 + df * 16 + l15] = O[df][r];
        }
    }
    __syncthreads();
    if (g == 0) {
#pragma unroll
        for (int r = 0; r < 4; r++) {
            const int row = wl * 16 + quad * 4 + r;
            const float inv = 1.0f / (lr[r] + exl[row]);
#pragma unroll
            for (int df = 0; df < 4; df++)
                AOb[(size_t)(t0 + row) * D_DIM + hbase + df * 16 + l15] =
                    f2b((O[df][r] + exch[row * 65 + df * 16 + l15]) * inv);
        }
    }
}

// ---------------------------------------------------------------------------
extern "C" void kernel_launch(void* const* d_in, const int* in_sizes, int n_in,
                              void* d_out, int out_size, void* d_ws, size_t ws_size,
                              hipStream_t stream) {
    const float* x     = (const float*)d_in[0];
    const float* extra = (const float*)d_in[1];
    // d_in[2]=mask (tril), d_in[3]=extra_mask (ones): deterministic -> unused
    const float* Wq  = (const float*)d_in[4];
    const float* Wk  = (const float*)d_in[5];
    const float* Wv  = (const float*)d_in[6];
    const float* Wek = (const float*)d_in[7];
    const float* Wev = (const float*)d_in[8];
    const float* Wr  = (const float*)d_in[9];
    const float* Wo  = (const float*)d_in[10];
    const float* rwb = (const float*)d_in[11];
    const float* rrb = (const float*)d_in[12];
    float* out = (float*)d_out;

    ushort* ws = (ushort*)d_ws;
    const size_t M1 = 1024 * 1024;
    size_t o = 0;
    ushort* posb = ws + o; o += 2 * M1;           // pos bf16 [2048][1024]; reused as AOb
    ushort* xb   = ws + o; o += 2 * M1;           // x bf16
    ushort* eb   = ws + o; o += M1;               // extra bf16
    ushort* WT   = ws + o; o += 7 * M1;           // [Wq|Wk|Wv|Wek|Wev|Wr|Wo]^T bf16
    ushort* Qb   = ws + o; o += 2 * M1;           // [2048][1024]
    ushort* Kb   = ws + o; o += 2 * M1;           // [2048][1024]
    ushort* VTb  = ws + o; o += 2 * M1;           // [1024][2048] transposed
    ushort* Rb   = ws + o; o += (size_t)(T_LEN + R_PAD) * 1024;  // [2112][1024]
    ushort* EKb  = ws + o; o += M1;               // [1024][1024]
    ushort* EVTb = ws + o; o += M1;               // [1024][1024] transposed
    ushort* AOb  = posb;                          // pos dead after mega-GEMM

    prep_kernel<<<5120, 256, 0, stream>>>(x, extra, posb, xb, eb);
    transpose7_kernel<<<dim3(32, 32, 8), 256, 0, stream>>>(
        Wq, Wk, Wv, Wek, Wev, Wr, Wo, WT, Rb + (size_t)T_LEN * 1024);

    gemm_mega<<<640, 256, 0, stream>>>(xb, posb, eb, WT, Qb, Kb, VTb, Rb, EKb, EVTb);

    attn_kernel<<<512, 512, 0, stream>>>(Qb, Kb, VTb, Rb, EKb, EVTb, rwb, rrb, AOb);

    gemm_wo<<<dim3(16, 16), 256, 0, stream>>>(AOb, WT + 6 * M1, out);
}

// Round 3
// 266.987 us; speedup vs baseline: 1.1151x; 1.1151x over previous
//
#include <hip/hip_runtime.h>
#include <hip/hip_bf16.h>
#include <math.h>

#define T_LEN 2048
#define TE_LEN 1024
#define D_DIM 1024
#define H_NUM 16
#define HD_DIM 64
#define R_PAD 64  // zero rows appended to R for u>T-1 (masked) selections

typedef unsigned short ushort;
typedef __attribute__((ext_vector_type(8))) short short8;    // 8 x bf16 MFMA frag
typedef __attribute__((ext_vector_type(4))) float f32x4;     // MFMA acc frag
typedef __attribute__((ext_vector_type(4))) ushort ushort4v;

__device__ __forceinline__ ushort f2b(float f) {  // fp32 -> bf16 RNE
    unsigned u = __builtin_bit_cast(unsigned, f);
    u += 0x7fffu + ((u >> 16) & 1u);
    return (ushort)(u >> 16);
}
__device__ __forceinline__ float b2f(ushort s) {
    unsigned u = ((unsigned)s) << 16;
    return __builtin_bit_cast(float, u);
}

// async global->LDS copy, 16B per lane: lands at (wave-uniform) ldsbase + lane*16.
__device__ __forceinline__ void gld16(const ushort* g, ushort* l) {
    __builtin_amdgcn_global_load_lds(
        (const __attribute__((address_space(1))) unsigned int*)g,
        (__attribute__((address_space(3))) unsigned int*)l, 16, 0, 0);
}

union U8 { short8 v; ushort u[8]; };

// ---------------------------------------------------------------------------
// prep: pos emb (bf16) + x/extra fp32->bf16 casts, one dispatch.
// ---------------------------------------------------------------------------
__global__ void prep_kernel(const float* __restrict__ x, const float* __restrict__ extra,
                            ushort* __restrict__ pos, ushort* __restrict__ xb,
                            ushort* __restrict__ eb) {
    const int q = blockIdx.x * 256 + threadIdx.x;  // quad index
    const int PQ = 524288;        // pos quads (2M elems)
    const int XQ = 1048576;       // + x quads (2M elems)
    if (q < PQ) {
        int idx = q * 4;
        int i = idx >> 10, j = idx & 1023;
        bool sinreg = (j < 512);
        int jj = sinreg ? j : j - 512;
        float p = (float)(2047 - i);
        ushort4v o;
#pragma unroll
        for (int u = 0; u < 4; u++) {
            // -(2/1024)*log2(10000) = -0.025952563241
            float inv = exp2f((float)(jj + u) * -0.025952563241f);
            float fa = p * inv;
            ((ushort*)&o)[u] = f2b(sinreg ? sinf(fa) : cosf(fa));
        }
        *(ushort4v*)&pos[idx] = o;
    } else if (q < XQ) {
        int idx = (q - PQ) * 4;
        float4 v = *(const float4*)&x[idx];
        ushort4v o = {f2b(v.x), f2b(v.y), f2b(v.z), f2b(v.w)};
        *(ushort4v*)&xb[idx] = o;
    } else {
        int idx = (q - XQ) * 4;
        float4 v = *(const float4*)&extra[idx];
        ushort4v o = {f2b(v.x), f2b(v.y), f2b(v.z), f2b(v.w)};
        *(ushort4v*)&eb[idx] = o;
    }
}

// 7 weight transposes + R-pad zeroing in ONE dispatch (z=0..6 transpose, z=7 zero).
__global__ __launch_bounds__(256) void transpose7_kernel(
    const float* __restrict__ W0, const float* __restrict__ W1,
    const float* __restrict__ W2, const float* __restrict__ W3,
    const float* __restrict__ W4, const float* __restrict__ W5,
    const float* __restrict__ W6, ushort* __restrict__ out,
    ushort* __restrict__ Rpad) {
    if (blockIdx.z == 7) {
        int gid = (blockIdx.y * 32 + blockIdx.x) * 256 + threadIdx.x;
        if (gid < (R_PAD * 1024) / 8) {
            short8 z = {0, 0, 0, 0, 0, 0, 0, 0};
            *(short8*)&Rpad[gid * 8] = z;
        }
        return;
    }
    const float* Ws[7] = {W0, W1, W2, W3, W4, W5, W6};
    const float* W = Ws[blockIdx.z];
    ushort* WT = out + (size_t)blockIdx.z * (1024 * 1024);
    __shared__ float tile[32][33];
    int c0 = blockIdx.x * 32, r0 = blockIdx.y * 32;
    int tid = threadIdx.x;
#pragma unroll
    for (int p = 0; p < 4; p++) {
        int idx = tid + p * 256;
        int r = idx >> 5, c = idx & 31;
        tile[r][c] = W[(size_t)(r0 + r) * D_DIM + c0 + c];
    }
    __syncthreads();
#pragma unroll
    for (int p = 0; p < 4; p++) {
        int idx = tid + p * 256;
        int r = idx >> 5, c = idx & 31;
        WT[(size_t)(c0 + r) * D_DIM + r0 + c] = f2b(tile[c][r]);
    }
}

// ---------------------------------------------------------------------------
// Mega-GEMM (m97 structure): QKV (384) + R (128) + EK|EV (128) = 640 blocks.
// 128x128 tile, BK=64, K=1024. Single-buffer LDS (32KB -> 4 blocks/CU),
// 2 barriers/ktile, gld16 async staging with XOR chunk-swizzle (2-way free).
// ---------------------------------------------------------------------------
__global__ __launch_bounds__(256) void gemm_mega(
    const ushort* __restrict__ xb, const ushort* __restrict__ posb,
    const ushort* __restrict__ eb, const ushort* __restrict__ WT,
    ushort* __restrict__ Qb, ushort* __restrict__ Kb, ushort* __restrict__ VTb,
    ushort* __restrict__ Rb, ushort* __restrict__ EKb, ushort* __restrict__ EVTb) {
    __shared__ ushort As[128 * 64];   // [row][chunk^(row&7)] 16KB
    __shared__ ushort Bs[128 * 64];
    const int tid = threadIdx.x;
    const int lane = tid & 63, w = tid >> 6;
    const int l15 = lane & 15, quad = lane >> 4;
    const int wm = w & 1, wn = w >> 1;
    const size_t M1 = 1024 * 1024;

    int idx = blockIdx.x;
    const ushort *A, *BT;
    ushort* dst;
    int m0, nb0, nc0, ldt = 1024;
    bool transp = false;
    if (idx < 384) {                       // QKV: x @ [Wq|Wk|Wv]
        m0 = (idx & 15) * 128; nb0 = (idx >> 4) * 128;
        A = xb; BT = WT;
        nc0 = nb0 & 1023;
        int seg = nb0 >> 10;
        if (seg == 0) dst = Qb;
        else if (seg == 1) dst = Kb;
        else { dst = VTb; transp = true; ldt = T_LEN; }
    } else if (idx < 512) {                // R: pos @ Wr
        int i = idx - 384;
        m0 = (i & 15) * 128; nb0 = (i >> 4) * 128; nc0 = nb0;
        A = posb; BT = WT + 5 * M1; dst = Rb;
    } else {                               // EK|EV: extra @ [Wek|Wev]
        int i = idx - 512;
        m0 = (i & 7) * 128; nb0 = (i >> 3) * 128; nc0 = nb0 & 1023;
        A = eb; BT = WT + 3 * M1;
        if (nb0 < 1024) dst = EKb;
        else { dst = EVTb; transp = true; ldt = TE_LEN; }
    }

    f32x4 acc[16];
#pragma unroll
    for (int i = 0; i < 16; i++) acc[i] = (f32x4){0.f, 0.f, 0.f, 0.f};

    for (int k0 = 0; k0 < 1024; k0 += 64) {
        __syncthreads();   // previous ktile's ds_reads done
#pragma unroll
        for (int i = 0; i < 4; i++) {
            int ci = i * 256 + tid;
            int row = ci >> 3, cs = (ci & 7) ^ (row & 7);
            gld16(A + (size_t)(m0 + row) * 1024 + k0 + cs * 8, &As[(i * 32 + w * 8) * 64]);
            gld16(BT + (size_t)(nb0 + row) * 1024 + k0 + cs * 8, &Bs[(i * 32 + w * 8) * 64]);
        }
        __syncthreads();   // staging landed (vmcnt drained by barrier)
#pragma unroll
        for (int kc = 0; kc < 2; kc++) {
            short8 bfr[4];
#pragma unroll
            for (int nf = 0; nf < 4; nf++) {
                const int row = wn * 64 + nf * 16 + l15;
                bfr[nf] = *(const short8*)&Bs[(row * 8 + ((kc * 4 + quad) ^ (row & 7))) * 8];
            }
#pragma unroll
            for (int mf = 0; mf < 4; mf++) {
                const int row = wm * 64 + mf * 16 + l15;
                short8 afr = *(const short8*)&As[(row * 8 + ((kc * 4 + quad) ^ (row & 7))) * 8];
#pragma unroll
                for (int nf = 0; nf < 4; nf++)
                    acc[mf * 4 + nf] = __builtin_amdgcn_mfma_f32_16x16x32_bf16(afr, bfr[nf], acc[mf * 4 + nf], 0, 0, 0);
            }
        }
    }

#pragma unroll
    for (int mf = 0; mf < 4; mf++) {
#pragma unroll
        for (int nf = 0; nf < 4; nf++) {
            f32x4 a = acc[mf * 4 + nf];
            const int mrow = m0 + wm * 64 + mf * 16 + quad * 4;
            const int nc = nc0 + wn * 64 + nf * 16 + l15;
            if (transp) {
                ushort4v v = {f2b(a[0]), f2b(a[1]), f2b(a[2]), f2b(a[3])};
                *(ushort4v*)&dst[(size_t)nc * ldt + mrow] = v;
            } else {
#pragma unroll
                for (int r = 0; r < 4; r++) dst[(size_t)(mrow + r) * 1024 + nc] = f2b(a[r]);
            }
        }
    }
}

// ---------------------------------------------------------------------------
// Wo GEMM (m97 structure): out[2048][1024] fp32 = AO @ Wo. 128x64 -> 256 blocks.
// ---------------------------------------------------------------------------
__global__ __launch_bounds__(256) void gemm_wo(const ushort* __restrict__ A,
                                               const ushort* __restrict__ BT,
                                               float* __restrict__ out) {
    __shared__ ushort As[128 * 64];
    __shared__ ushort Bs[64 * 64];
    const int tid = threadIdx.x;
    const int lane = tid & 63, w = tid >> 6;
    const int l15 = lane & 15, quad = lane >> 4;
    const int wm = w & 1, wn = w >> 1;  // 2x2 waves: 64 rows x 32 cols each
    const int m0 = blockIdx.y * 128, n0 = blockIdx.x * 64;

    f32x4 acc[8];
#pragma unroll
    for (int i = 0; i < 8; i++) acc[i] = (f32x4){0.f, 0.f, 0.f, 0.f};

    for (int k0 = 0; k0 < 1024; k0 += 64) {
        __syncthreads();
#pragma unroll
        for (int i = 0; i < 4; i++) {
            int ci = i * 256 + tid;
            int row = ci >> 3, cs = (ci & 7) ^ (row & 7);
            gld16(A + (size_t)(m0 + row) * 1024 + k0 + cs * 8, &As[(i * 32 + w * 8) * 64]);
        }
#pragma unroll
        for (int i = 0; i < 2; i++) {
            int ci = i * 256 + tid;
            int row = ci >> 3, cs = (ci & 7) ^ (row & 7);
            gld16(BT + (size_t)(n0 + row) * 1024 + k0 + cs * 8, &Bs[(i * 32 + w * 8) * 64]);
        }
        __syncthreads();
#pragma unroll
        for (int kc = 0; kc < 2; kc++) {
            short8 bfr[2];
#pragma unroll
            for (int nf = 0; nf < 2; nf++) {
                const int row = wn * 32 + nf * 16 + l15;
                bfr[nf] = *(const short8*)&Bs[(row * 8 + ((kc * 4 + quad) ^ (row & 7))) * 8];
            }
#pragma unroll
            for (int mf = 0; mf < 4; mf++) {
                const int row = wm * 64 + mf * 16 + l15;
                short8 afr = *(const short8*)&As[(row * 8 + ((kc * 4 + quad) ^ (row & 7))) * 8];
#pragma unroll
                for (int nf = 0; nf < 2; nf++)
                    acc[mf * 2 + nf] = __builtin_amdgcn_mfma_f32_16x16x32_bf16(afr, bfr[nf], acc[mf * 2 + nf], 0, 0, 0);
            }
        }
    }

#pragma unroll
    for (int mf = 0; mf < 4; mf++) {
#pragma unroll
        for (int nf = 0; nf < 2; nf++) {
            f32x4 a = acc[mf * 2 + nf];
            const int mrow = m0 + wm * 64 + mf * 16 + quad * 4;
            const int nc = n0 + wn * 32 + nf * 16 + l15;
#pragma unroll
            for (int r = 0; r < 4; r++) out[(size_t)(mrow + r) * 1024 + nc] = a[r];
        }
    }
}

// ---------------------------------------------------------------------------
// Fused flash attention, 2-way KEY-SPLIT, 512 threads = two 4-wave groups.
// R3: R back in LDS (the R2 direct-global reads caused spills + L2 misses),
// but in a 96-slot mod-96 circular band (12KB/group, not 16KB) so TOTAL LDS
// is exactly 64KB -> guaranteed 2 blocks/CU (R1 showed 75776B rounds past
// the 2-block cliff). 96 slots = zero slack between the 80-row read window
// (rel-carry covers cf=0) and the 32-row stage, so in-seq tiles use a 2nd
// barrier: rel ds_reads issue first, barrier2 drains them (lgkm drain is
// implied by __syncthreads), THEN K/V/R staging for tile i+1 issues and its
// HBM latency hides under the MFMA/exp/PV section. P tiles: stride-32 with
// XOR column swizzle (8KB total). Fixed-max softmax partials combine by
// addition: group 1 passes (O, sum p) through LDS, group 0 stores.
// ---------------------------------------------------------------------------
__global__ __launch_bounds__(512) void attn_kernel(
    const ushort* __restrict__ Qb, const ushort* __restrict__ Kb,
    const ushort* __restrict__ VT, const ushort* __restrict__ Rb,
    const ushort* __restrict__ EKb, const ushort* __restrict__ EVT,
    const float* __restrict__ rwb, const float* __restrict__ rrb,
    ushort* __restrict__ AOb) {
    // LDS carve (ushort units), 65536 B total -> 2 blocks/CU:
    //   [    0, 8192) Kst: g*4096 + buf*2048   (2 groups x 2 bufs x 32x64)
    //   [ 8192,16384) Vst: g*4096 + buf*2048   (2 groups x 2 bufs x 64x32)
    //   [16384,28672) Rst: g*6144              (2 groups x 96x64, mod-96 frame)
    //   [28672,32768) Pw : w*512               (8 waves x 16x32, XOR-swizzled)
    //   exchange (post-loop, aliases dead K/V): exch f32[64][65] @0,
    //   exl f32[64] @ ushort-offset 12288.
    __shared__ __align__(16) ushort lds[32768];

    const int tid = threadIdx.x;
    const int lane = tid & 63, w = tid >> 6;
    const int g = w >> 2, wl = w & 3;      // group, group-local wave
    const int gtid = tid & 255;            // group-local thread id
    const int l15 = lane & 15, quad = lane >> 4;
    const int blk = blockIdx.x;
    const int xcd = blk & 7, rnd = blk >> 8, qslot = (blk >> 3) & 31;
    const int h = xcd * 2 + rnd;
    const int qt = rnd ? qslot : 31 - qslot;
    const int t0 = qt * 64, tf = t0 + wl * 16;
    const int hbase = h * HD_DIM;
    const int base0 = 1984 - t0;           // R row of (group 0) band origin
    const int ninl = qt + 1;               // in-seq tiles per group
    const int ntotl = ninl + 16;           // + 16 extra tiles per group
    const int tt_s = g * ninl;             // group's first global in-seq tile
    const int baseg = base0 + 32 * tt_s;   // R row origin for this group

    ushort* Kst = lds + g * 4096;          // [buf*2048 + ...]
    ushort* Vst = lds + 8192 + g * 4096;
    ushort* Rst = lds + 16384 + g * 6144;  // 96-row circular band
    ushort* Pw  = lds + 28672 + w * 512;   // this wave's 16x32 P tile

    // A-frags pre-scaled by 1/sqrt(HD)=0.125 (both groups load same Q rows):
    short8 qw[2], qr[2], qp[2];
#pragma unroll
    for (int kh = 0; kh < 2; kh++) {
        int dof = hbase + kh * 32 + quad * 8;
        U8 raw; raw.v = *(const short8*)&Qb[(size_t)(tf + l15) * D_DIM + dof];
        U8 a, b, c;
#pragma unroll
        for (int j = 0; j < 8; j++) {
            float f = b2f(raw.u[j]);
            a.u[j] = f2b((f + rwb[dof + j]) * 0.125f);
            b.u[j] = f2b((f + rrb[dof + j]) * 0.125f);
            c.u[j] = f2b(f * 0.125f);
        }
        qw[kh] = a.v; qr[kh] = b.v; qp[kh] = c.v;
    }

    float lr[4] = {0.f, 0.f, 0.f, 0.f};
    f32x4 O[4];
#pragma unroll
    for (int i = 0; i < 4; i++) O[i] = (f32x4){0.f, 0.f, 0.f, 0.f};
    f32x4 rel_carry = (f32x4){0.f, 0.f, 0.f, 0.f};

    auto stageKV = [&](int i2, int buf) {   // i2 = group-local tile index
        const bool ins = i2 < ninl;
        const int j0 = ins ? (tt_s + i2) * 32 : (g * 16 + (i2 - ninl)) * 32;
        const ushort* ksrc = ins ? Kb : EKb;
        const ushort* vsrc = ins ? VT : EVT;
        const int ldv = ins ? T_LEN : TE_LEN;
        {   // K: 32 rows x 8 chunks, 1 op/thread (group = 256 threads)
            int row = gtid >> 3, cs = (gtid & 7) ^ (row & 7);
            gld16(ksrc + (size_t)(j0 + row) * 1024 + hbase + cs * 8,
                  &Kst[buf * 2048 + wl * 512]);
        }
        {   // V: 64 rows x 4 chunks, 1 op/thread
            int row = gtid >> 2, cs = (gtid & 3) ^ (row & 3);
            gld16(vsrc + (size_t)(hbase + row) * ldv + j0 + cs * 8,
                  &Vst[buf * 2048 + wl * 512]);
        }
    };
    // stage 32 R rows at slots [slotbase, slotbase+32) (slotbase mult of 32,
    // never wraps). Swizzle key = row&7 == slot&7 (96 and 32 are mult of 8).
    auto stageR = [&](int slotbase, int rowbase) {
        int k = gtid >> 3;
        int cs = (gtid & 7) ^ (k & 7);
        gld16(Rb + (size_t)(rowbase + k) * 1024 + hbase + cs * 8,
              &Rst[(slotbase + wl * 8) * 64]);
    };

    // init: 96-row R band (slots 0..95 = rows baseg+0..95) + K/V tile 0
#pragma unroll
    for (int i = 0; i < 3; i++) {
        int ci = i * 256 + gtid;
        int k = ci >> 3, cs = (ci & 7) ^ (k & 7);
        gld16(Rb + (size_t)(baseg + k) * 1024 + hbase + cs * 8,
              &Rst[(i * 32 + wl * 8) * 64]);
    }
    stageKV(0, 0);

    // per-r constants for the band shift (loop-invariant)
    int srcA[4]; bool lowcA[4];
#pragma unroll
    for (int r = 0; r < 4; r++) {
        const int m = quad * 4 + r;
        const int cb = 15 - m + l15;  // band col in [0,30]
        srcA[r] = (lane & 48) | (cb & 15);
        lowcA[r] = (cb < 16);
    }

    int sb = 0;                      // window start slot = (32*i) % 96
#pragma unroll 1
    for (int i = 0; i < ntotl; i++) {
        const int b = i & 1;
        __syncthreads();                  // stage(i) landed; buf 1-b free
        const bool ins = i < ninl;
        const bool stR = (i + 1 < ninl);  // uniform (ninl same for both groups)

        // rel B-frags from the circular band. cf=0 comes from rel_carry
        // (prev tile's cf=2: same rows, same qr); at i==0 read it too.
        short8 rfa[2], rf1[2], rf2[2];
        if (ins) {
            const int key = l15 & 7;      // slot&7 == o&7 == l15&7
            const int o1 = 64 - 16 * wl + l15;   // cf=1
            const int o2 = 80 - 16 * wl + l15;   // cf=2
            int s1 = sb + o1; if (s1 >= 96) s1 -= 96;
            int s2 = sb + o2; if (s2 >= 96) s2 -= 96;
#pragma unroll
            for (int kh = 0; kh < 2; kh++) {
                rf1[kh] = *(const short8*)&Rst[(s1 * 8 + ((kh * 4 + quad) ^ key)) * 8];
                rf2[kh] = *(const short8*)&Rst[(s2 * 8 + ((kh * 4 + quad) ^ key)) * 8];
            }
            if (i == 0) {
                const int o0 = 48 - 16 * wl + l15;  // sb==0 at i==0
#pragma unroll
                for (int kh = 0; kh < 2; kh++)
                    rfa[kh] = *(const short8*)&Rst[(o0 * 8 + ((kh * 4 + quad) ^ key)) * 8];
            }
        }

        if (stR) {
            // barrier2: all waves' rel reads complete (syncthreads drains
            // lgkm) before the stage overwrites the oldest 32 slots.
            __syncthreads();
            stageKV(i + 1, 1 - b);
            stageR(sb, baseg + 96 + 32 * i);
        } else if (i + 1 < ntotl) {
            stageKV(i + 1, 1 - b);
        }

        const int j0 = (tt_s + i) * 32;   // only meaningful when ins

        f32x4 con[2];
#pragma unroll
        for (int c = 0; c < 2; c++) con[c] = (f32x4){0.f, 0.f, 0.f, 0.f};
#pragma unroll
        for (int kh = 0; kh < 2; kh++) {
            const short8* qa = ins ? &qw[kh] : &qp[kh];
#pragma unroll
            for (int nh = 0; nh < 2; nh++) {
                const int row = nh * 16 + l15;
                short8 kf = *(const short8*)&Kst[b * 2048 + (row * 8 + ((kh * 4 + quad) ^ (row & 7))) * 8];
                con[nh] = __builtin_amdgcn_mfma_f32_16x16x32_bf16(*qa, kf, con[nh], 0, 0, 0);
            }
        }

        if (ins) {
            f32x4 relA, rel1, rel2;
            rel1 = (f32x4){0.f, 0.f, 0.f, 0.f};
            rel2 = (f32x4){0.f, 0.f, 0.f, 0.f};
            if (i == 0) {
                relA = (f32x4){0.f, 0.f, 0.f, 0.f};
#pragma unroll
                for (int kh = 0; kh < 2; kh++)
                    relA = __builtin_amdgcn_mfma_f32_16x16x32_bf16(qr[kh], rfa[kh], relA, 0, 0, 0);
            } else {
                relA = rel_carry;
            }
#pragma unroll
            for (int kh = 0; kh < 2; kh++) {
                rel1 = __builtin_amdgcn_mfma_f32_16x16x32_bf16(qr[kh], rf1[kh], rel1, 0, 0, 0);
                rel2 = __builtin_amdgcn_mfma_f32_16x16x32_bf16(qr[kh], rf2[kh], rel2, 0, 0, 0);
            }
            rel_carry = rel2;

            const bool needmask = (j0 + 31 > tf);
#pragma unroll
            for (int r = 0; r < 4; r++) {
                const int m = quad * 4 + r;
                float b0 = __shfl(relA[r], srcA[r]);
                float b1 = __shfl(rel1[r], srcA[r]);
                float b2 = __shfl(rel2[r], srcA[r]);
                float rv0 = lowcA[r] ? b0 : b1, rv1 = lowcA[r] ? b1 : b2;
                float p0 = __expf(con[0][r] + rv0);
                float p1 = __expf(con[1][r] + rv1);
                if (needmask) {
                    const int t = tf + m;
                    if (j0 + l15 > t)      p0 = 0.f;
                    if (j0 + 16 + l15 > t) p1 = 0.f;
                }
                lr[r] += p0 + p1;
                const int sw = (r & 3) << 3;   // == (m&3)<<3
                Pw[m * 32 + (l15 ^ sw)]        = f2b(p0);
                Pw[m * 32 + ((16 + l15) ^ sw)] = f2b(p1);
            }
        } else {
#pragma unroll
            for (int r = 0; r < 4; r++) {
                const int m = quad * 4 + r;
                float p0 = __expf(con[0][r]);
                float p1 = __expf(con[1][r]);
                lr[r] += p0 + p1;
                const int sw = (r & 3) << 3;
                Pw[m * 32 + (l15 ^ sw)]        = f2b(p0);
                Pw[m * 32 + ((16 + l15) ^ sw)] = f2b(p1);
            }
        }

        short8 pa = *(const short8*)&Pw[l15 * 32 + ((quad ^ (l15 & 3)) << 3)];
#pragma unroll
        for (int df = 0; df < 4; df++) {
            const int row = df * 16 + l15;
            short8 vb = *(const short8*)&Vst[b * 2048 + (row * 4 + (quad ^ (row & 3))) * 8];
            O[df] = __builtin_amdgcn_mfma_f32_16x16x32_bf16(pa, vb, O[df], 0, 0, 0);
        }

        sb += 32; if (sb >= 96) sb -= 96;
    }

    // ---- finalize: reduce lr over the 16 j-lanes, cross-group combine ----
#pragma unroll
    for (int r = 0; r < 4; r++)
#pragma unroll
        for (int dd = 1; dd < 16; dd <<= 1) lr[r] += __shfl_xor(lr[r], dd);

    float* exch = (float*)(lds);          // 64x65 f32 (pad-65 kills bank conflicts)
    float* exl  = (float*)(lds + 12288);  // 64 f32 row sums
    __syncthreads();                      // all tiles done; safe to alias LDS
    if (g == 1) {
#pragma unroll
        for (int r = 0; r < 4; r++) {
            const int row = wl * 16 + quad * 4 + r;
            if (l15 == 0) exl[row] = lr[r];
#pragma unroll
            for (int df = 0; df < 4; df++)
                exch[row * 65 + df * 16 + l15] = O[df][r];
        }
    }
    __syncthreads();
    if (g == 0) {
#pragma unroll
        for (int r = 0; r < 4; r++) {
            const int row = wl * 16 + quad * 4 + r;
            const float inv = 1.0f / (lr[r] + exl[row]);
#pragma unroll
            for (int df = 0; df < 4; df++)
                AOb[(size_t)(t0 + row) * D_DIM + hbase + df * 16 + l15] =
                    f2b((O[df][r] + exch[row * 65 + df * 16 + l15]) * inv);
        }
    }
}

// ---------------------------------------------------------------------------
extern "C" void kernel_launch(void* const* d_in, const int* in_sizes, int n_in,
                              void* d_out, int out_size, void* d_ws, size_t ws_size,
                              hipStream_t stream) {
    const float* x     = (const float*)d_in[0];
    const float* extra = (const float*)d_in[1];
    // d_in[2]=mask (tril), d_in[3]=extra_mask (ones): deterministic -> unused
    const float* Wq  = (const float*)d_in[4];
    const float* Wk  = (const float*)d_in[5];
    const float* Wv  = (const float*)d_in[6];
    const float* Wek = (const float*)d_in[7];
    const float* Wev = (const float*)d_in[8];
    const float* Wr  = (const float*)d_in[9];
    const float* Wo  = (const float*)d_in[10];
    const float* rwb = (const float*)d_in[11];
    const float* rrb = (const float*)d_in[12];
    float* out = (float*)d_out;

    ushort* ws = (ushort*)d_ws;
    const size_t M1 = 1024 * 1024;
    size_t o = 0;
    ushort* posb = ws + o; o += 2 * M1;           // pos bf16 [2048][1024]; reused as AOb
    ushort* xb   = ws + o; o += 2 * M1;           // x bf16
    ushort* eb   = ws + o; o += M1;               // extra bf16
    ushort* WT   = ws + o; o += 7 * M1;           // [Wq|Wk|Wv|Wek|Wev|Wr|Wo]^T bf16
    ushort* Qb   = ws + o; o += 2 * M1;           // [2048][1024]
    ushort* Kb   = ws + o; o += 2 * M1;           // [2048][1024]
    ushort* VTb  = ws + o; o += 2 * M1;           // [1024][2048] transposed
    ushort* Rb   = ws + o; o += (size_t)(T_LEN + R_PAD) * 1024;  // [2112][1024]
    ushort* EKb  = ws + o; o += M1;               // [1024][1024]
    ushort* EVTb = ws + o; o += M1;               // [1024][1024] transposed
    ushort* AOb  = posb;                          // pos dead after mega-GEMM

    prep_kernel<<<5120, 256, 0, stream>>>(x, extra, posb, xb, eb);
    transpose7_kernel<<<dim3(32, 32, 8), 256, 0, stream>>>(
        Wq, Wk, Wv, Wek, Wev, Wr, Wo, WT, Rb + (size_t)T_LEN * 1024);

    gemm_mega<<<640, 256, 0, stream>>>(xb, posb, eb, WT, Qb, Kb, VTb, Rb, EKb, EVTb);

    attn_kernel<<<512, 512, 0, stream>>>(Qb, Kb, VTb, Rb, EKb, EVTb, rwb, rrb, AOb);

    gemm_wo<<<dim3(16, 16), 256, 0, stream>>>(AOb, WT + 6 * M1, out);
}